// Round 9
// baseline (63.382 us; speedup 1.0000x reference)
//
#include <hip/hip_runtime.h>
#include <hip/hip_fp16.h>

typedef _Float16 half8 __attribute__((ext_vector_type(8)));
typedef float floatx4 __attribute__((ext_vector_type(4)));

#define KH 256              // H (inner / K dim)
#define NN 1024             // N heads
#define BM 256              // b-rows per block: 4 waves x 4 row-tiles x 16
#define THREADS 256
#define NSPLIT 8            // col-windows of 128
#define GPB 8               // 16-col groups per window
#define GRP_F16 4096        // one group: 16 n x 256 k f16 = 8 KB
#define WIN_F16 (GPB * GRP_F16)   // 32768 f16 = 64 KB

// ---------------- pack kernel: W fp32 -> f16, MFMA-fragment order ----------
// packed f16 index: ((g*8 + ks)*64 + lane)*8 + j
//   where n = g*16 + (lane&15), k = ks*32 + (lane>>4)*8 + j
__global__ __launch_bounds__(256)
void pack_w(const float* __restrict__ W, _Float16* __restrict__ P) {
    const int u  = blockIdx.x * 256 + threadIdx.x;   // 32768 threads total
    const int g  = u >> 9;
    const int ks = (u >> 6) & 7;
    const int l  = u & 63;
    const int n  = g * 16 + (l & 15);
    const int kb = ks * 32 + ((l >> 4) << 3);
    const float* src = W + (size_t)n * KH + kb;
    floatx4 lo = *(const floatx4*)src;
    floatx4 hi = *(const floatx4*)(src + 4);
    half8 h;
    h[0] = (_Float16)lo[0]; h[1] = (_Float16)lo[1];
    h[2] = (_Float16)lo[2]; h[3] = (_Float16)lo[3];
    h[4] = (_Float16)hi[0]; h[5] = (_Float16)hi[1];
    h[6] = (_Float16)hi[2]; h[7] = (_Float16)hi[3];
    *(half8*)(P + (size_t)u * 8) = h;                // fully coalesced 16B/lane
}

// ---- main: stage-once + ONE barrier; each W fragment read ONCE from LDS
// ---- and applied to 4 register-resident row-tiles (ds_read traffic /4) ----
__global__ __launch_bounds__(THREADS, 2)
void lfh_main(const float* __restrict__ x, const _Float16* __restrict__ P,
              const float* __restrict__ bias, float* __restrict__ out) {
    __shared__ _Float16 Ws[WIN_F16];      // 64 KB W window, staged once
    __shared__ float    bls[128];         // this window's bias

    const int t   = threadIdx.x;
    const int w   = t >> 6;               // wave -> rows [w*64, w*64+64)
    const int l   = t & 63;
    const int l15 = l & 15;
    const int lq  = l >> 4;
    const int brow0   = blockIdx.x * BM + w * 64;
    const int colBase = blockIdx.y * 128;

    // ---- stage 64 KB W window: 16 x (256 thr x 16B) async, fires first ----
    {
        const _Float16* gsrc = P + (size_t)blockIdx.y * WIN_F16;
        #pragma unroll
        for (int r = 0; r < 16; ++r) {
            __builtin_amdgcn_global_load_lds(
                (const __attribute__((address_space(1))) void*)(gsrc + r * 2048 + t * 8),
                (__attribute__((address_space(3))) void*)(Ws + r * 2048 + t * 8),
                16, 0, 0);
        }
    }
    if (t < 32) *(floatx4*)&bls[t * 4] = *(const floatx4*)(bias + colBase + t * 4);

    // ---- A fragments: 4 row-tiles per wave, fp32 -> f16, in registers -----
    half8 afrag[4][8];
    #pragma unroll
    for (int rt = 0; rt < 4; ++rt) {
        const float* xr = x + (size_t)(brow0 + rt * 16 + l15) * KH;
        #pragma unroll
        for (int ks = 0; ks < 8; ++ks) {
            const int kb = ks * 32 + lq * 8;
            floatx4 lo = *(const floatx4*)(xr + kb);
            floatx4 hi = *(const floatx4*)(xr + kb + 4);
            half8 f;
            f[0] = (_Float16)lo[0]; f[1] = (_Float16)lo[1];
            f[2] = (_Float16)lo[2]; f[3] = (_Float16)lo[3];
            f[4] = (_Float16)hi[0]; f[5] = (_Float16)hi[1];
            f[6] = (_Float16)hi[2]; f[7] = (_Float16)hi[3];
            afrag[rt][ks] = f;
        }
    }

    __syncthreads();   // the ONLY barrier (no stores outstanding yet)

    #pragma unroll
    for (int g = 0; g < GPB; ++g) {
        // 8 conflict-free ds_read_b128: each fragment read ONCE per wave
        const _Float16* fb = Ws + g * GRP_F16 + l * 8;
        half8 wf[8];
        #pragma unroll
        for (int ks = 0; ks < 8; ++ks) wf[ks] = *(const half8*)(fb + ks * 512);

        floatx4 acc[4] = {(floatx4)0.0f, (floatx4)0.0f, (floatx4)0.0f, (floatx4)0.0f};
        #pragma unroll
        for (int ks = 0; ks < 8; ++ks)
            #pragma unroll
            for (int rt = 0; rt < 4; ++rt)    // 4 indep MFMA per fragment
                acc[rt] = __builtin_amdgcn_mfma_f32_16x16x32_f16(
                              wf[ks], afrag[rt][ks], acc[rt], 0, 0, 0);

        // epilogue: bias + sigmoid + plain float4 stores (L2 merges lines)
        const int cb = g * 16 + lq * 4;
        floatx4 bv = *(const floatx4*)&bls[cb];
        #pragma unroll
        for (int rt = 0; rt < 4; ++rt) {
            floatx4 r;
            #pragma unroll
            for (int j = 0; j < 4; ++j)
                r[j] = __builtin_amdgcn_rcpf(1.0f + __expf(-(acc[rt][j] + bv[j])));
            *(floatx4*)(out + (size_t)(brow0 + rt * 16 + l15) * NN + colBase + cb) = r;
        }
    }
}

extern "C" void kernel_launch(void* const* d_in, const int* in_sizes, int n_in,
                              void* d_out, int out_size, void* d_ws, size_t ws_size,
                              hipStream_t stream) {
    const float* x = (const float*)d_in[0];
    const float* W = (const float*)d_in[1];
    const float* b = (const float*)d_in[2];
    float* out = (float*)d_out;
    _Float16* P = (_Float16*)d_ws;            // 512 KB packed f16 W

    pack_w<<<dim3(128), dim3(256), 0, stream>>>(W, P);

    const int Btot = in_sizes[0] / KH;        // 32768
    lfh_main<<<dim3(Btot / BM, NSPLIT), dim3(THREADS), 0, stream>>>(x, P, b, out);
}

// Round 10
// 55.716 us; speedup vs baseline: 1.1376x; 1.1376x over previous
//
#include <hip/hip_runtime.h>
#include <hip/hip_fp16.h>

typedef _Float16 half8 __attribute__((ext_vector_type(8)));
typedef float floatx4 __attribute__((ext_vector_type(4)));

#define KH 256              // H (inner / K dim)
#define NN 1024             // N heads
#define BM 64               // b-rows per block (4 waves x 16)
#define THREADS 256
#define NSPLIT 2            // col windows of 512
#define NTILES 16           // 32-col tiles per window
#define GRP_F16 4096        // one 16-col group: 16 n x 256 k f16 = 8 KB
#define TILE_F16 8192       // 2 groups = 16 KB per tile

// ---------------- pack kernel: W fp32 -> f16, MFMA-fragment order ----------
// packed f16 index: ((g*8 + ks)*64 + lane)*8 + j
//   where n = g*16 + (lane&15), k = ks*32 + (lane>>4)*8 + j
__global__ __launch_bounds__(256)
void pack_w(const float* __restrict__ W, _Float16* __restrict__ P) {
    const int u  = blockIdx.x * 256 + threadIdx.x;   // 32768 threads total
    const int g  = u >> 9;
    const int ks = (u >> 6) & 7;
    const int l  = u & 63;
    const int n  = g * 16 + (l & 15);
    const int kb = ks * 32 + ((l >> 4) << 3);
    const float* src = W + (size_t)n * KH + kb;
    floatx4 lo = *(const floatx4*)src;
    floatx4 hi = *(const floatx4*)(src + 4);
    half8 h;
    h[0] = (_Float16)lo[0]; h[1] = (_Float16)lo[1];
    h[2] = (_Float16)lo[2]; h[3] = (_Float16)lo[3];
    h[4] = (_Float16)hi[0]; h[5] = (_Float16)hi[1];
    h[6] = (_Float16)hi[2]; h[7] = (_Float16)hi[3];
    *(half8*)(P + (size_t)u * 8) = h;                // fully coalesced 16B/lane
}

// ---- main: R2 skeleton, 34KB LDS -> 4 blocks/CU (4 waves/SIMD), counted
// ---- vmcnt(2) so only 1-iter-old stores ever drain ------------------------
__global__ __launch_bounds__(THREADS, 4)
void lfh_main(const float* __restrict__ x, const _Float16* __restrict__ P,
              const float* __restrict__ bias, float* __restrict__ out) {
    __shared__ _Float16 WsA[TILE_F16];   // 16 KB
    __shared__ _Float16 WsB[TILE_F16];   // 16 KB
    __shared__ float    bls[512];        // this window's bias (2 KB)

    const int t   = threadIdx.x;
    const int l   = t & 63;
    const int l15 = l & 15;
    const int lq  = l >> 4;
    const int brow = blockIdx.x * BM + (t >> 6) * 16 + l15;
    const int colBase = blockIdx.y * 512;
    const int g0 = blockIdx.y * 32;      // first 16-col group of this window

    auto stage = [&](int tt, _Float16* dst) {   // 16 KB: 4 x (256 thr x 16B)
        const _Float16* gsrc = P + (size_t)(g0 + tt * 2) * GRP_F16;
        #pragma unroll
        for (int r = 0; r < 4; ++r) {
            __builtin_amdgcn_global_load_lds(
                (const __attribute__((address_space(1))) void*)(gsrc + r * 2048 + t * 8),
                (__attribute__((address_space(3))) void*)(dst + r * 2048 + t * 8),
                16, 0, 0);
        }
    };

    // ---- prologue: bias -> LDS, A fragments -> regs, stage tile 0 ---------
    if (t < 128) {
        floatx4 bv = *(const floatx4*)(bias + colBase + t * 4);
        *(floatx4*)&bls[t * 4] = bv;
    }
    half8 afrag[8];
    {
        const float* xr = x + (size_t)brow * KH;
        #pragma unroll
        for (int ks = 0; ks < 8; ++ks) {
            const int kb = ks * 32 + lq * 8;
            floatx4 lo = *(const floatx4*)(xr + kb);
            floatx4 hi = *(const floatx4*)(xr + kb + 4);
            half8 f;
            f[0] = (_Float16)lo[0]; f[1] = (_Float16)lo[1];
            f[2] = (_Float16)lo[2]; f[3] = (_Float16)lo[3];
            f[4] = (_Float16)hi[0]; f[5] = (_Float16)hi[1];
            f[6] = (_Float16)hi[2]; f[7] = (_Float16)hi[3];
            afrag[ks] = f;
        }
    }
    stage(0, WsA);
    __syncthreads();     // prologue only: drains everything incl. stage(0)

    float* orow = out + (size_t)brow * NN + colBase;

    #pragma unroll
    for (int tt = 0; tt < NTILES; ++tt) {
        if (tt > 0) {
            // FIFO: stores(tt-1) x2 (newest), stage(tt) x4, stores(tt-2) x2.
            // vmcnt(2): stage(tt) landed; newest stores stay in flight.
            asm volatile("s_waitcnt vmcnt(2)" ::: "memory");
            __builtin_amdgcn_s_barrier();
            __builtin_amdgcn_sched_barrier(0);
        }
        const _Float16* RB = (tt & 1) ? WsB : WsA;
        if (tt + 1 < NTILES) stage(tt + 1, (tt & 1) ? WsA : WsB);

        #pragma unroll
        for (int g = 0; g < 2; ++g) {
            const _Float16* fb = RB + g * GRP_F16 + l * 8;  // linear, conflict-free
            floatx4 a = (floatx4)0.0f;
            #pragma unroll
            for (int ks = 0; ks < 8; ++ks)
                a = __builtin_amdgcn_mfma_f32_16x16x32_f16(
                        *(const half8*)(fb + ks * 512), afrag[ks], a, 0, 0, 0);
            const int cb = (tt * 2 + g) * 16 + lq * 4;      // col within window
            floatx4 bv = *(const floatx4*)&bls[cb];
            floatx4 r;
            #pragma unroll
            for (int j = 0; j < 4; ++j)
                r[j] = __builtin_amdgcn_rcpf(1.0f + __expf(-(a[j] + bv[j])));
            __builtin_nontemporal_store(r, (floatx4*)(orow + cb));  // fire & forget
        }
    }
}

extern "C" void kernel_launch(void* const* d_in, const int* in_sizes, int n_in,
                              void* d_out, int out_size, void* d_ws, size_t ws_size,
                              hipStream_t stream) {
    const float* x = (const float*)d_in[0];
    const float* W = (const float*)d_in[1];
    const float* b = (const float*)d_in[2];
    float* out = (float*)d_out;
    _Float16* P = (_Float16*)d_ws;            // 512 KB packed f16 W

    pack_w<<<dim3(128), dim3(256), 0, stream>>>(W, P);

    const int Btot = in_sizes[0] / KH;        // 32768
    lfh_main<<<dim3(Btot / BM, NSPLIT), dim3(THREADS), 0, stream>>>(x, P, b, out);
}